// Round 12
// baseline (125.103 us; speedup 1.0000x reference)
//
#include <hip/hip_runtime.h>
#include <hip/hip_fp16.h>

#define H 32
#define TPB 256
#define TPB_P 256         // threads for place (367 WGs -> all CUs busy)
#define TPB2 256          // threads for fused build+gather
#define EPT 16            // edges per thread in place (4096 edges per WG)
#define SLOTS 128         // dst slots per bucket
#define CAP 2048          // fixed capacity per bucket (mean 1280, +21 sigma)
#define MAXBUCK 2048      // static LDS bound (actual NBUCK = 1563)

// ---------------- fused encoder: both node types + gcurp init ----------------
// 32-lane group per node; nodes [0,NB) = bridge (FIN=16), [NB,NB+NR) = road (FIN=8).
__global__ void __launch_bounds__(TPB) encoder_kernel(
        const float* __restrict__ x_b, const float* __restrict__ x_r,
        const float* __restrict__ W_b, const float* __restrict__ b_b,
        const float* __restrict__ W_r, const float* __restrict__ b_r,
        __half* __restrict__ h_b16, __half* __restrict__ h_r16,
        int NB, int NR,
        int* __restrict__ gcurp, int NBUCK) {
    int gid = blockIdx.x * blockDim.x + threadIdx.x;
    if (gid < NBUCK) gcurp[gid * 16] = gid * CAP;

    __shared__ float sWb[16 * H];
    __shared__ float sWr[8 * H];
    __shared__ float sbb[H];
    __shared__ float sbr[H];
    int t = threadIdx.x;
    for (int i = t; i < 16 * H; i += TPB) sWb[i] = W_b[i];
    for (int i = t; i < 8 * H; i += TPB) sWr[i] = W_r[i];
    if (t < H) { sbb[t] = b_b[t]; sbr[t] = b_r[t]; }
    __syncthreads();

    int lane  = t & (H - 1);
    int local = t >> 5;
    long long node = (long long)blockIdx.x * (TPB / H) + local;
    if (node < NB) {
        const float* xr = x_b + node * 16;
        float acc = sbb[lane];
        #pragma unroll
        for (int k = 0; k < 16; ++k)
            acc = fmaf(xr[k], sWb[k * H + lane], acc);
        h_b16[node * H + lane] = __float2half(fmaxf(acc, 0.0f));
    } else if (node < (long long)NB + NR) {
        long long m = node - NB;
        const float* xr = x_r + m * 8;
        float acc = sbr[lane];
        #pragma unroll
        for (int k = 0; k < 8; ++k)
            acc = fmaf(xr[k], sWr[k * H + lane], acc);
        h_r16[m * H + lane] = __float2half(fmaxf(acc, 0.0f));
    }
}

// ---------------- place edges into fixed-capacity bucket bins ----------------
// concatenated dst space: rb -> d, bb -> NB + d.
// packed entry = (src << 7) | (slot & 127).
__global__ void __launch_bounds__(TPB_P) place_kernel(
        const int* __restrict__ src_rb, const int* __restrict__ dst_rb,
        const int* __restrict__ src_bb, const int* __restrict__ dst_bb,
        int* __restrict__ gcurp, int* __restrict__ bins,
        int E_RB, int E_BB, int NB, int NBUCK) {
    __shared__ int lcnt[MAXBUCK];
    __shared__ int wbase[MAXBUCK];
    int t = threadIdx.x;
    for (int i = t; i < MAXBUCK; i += TPB_P) lcnt[i] = 0;
    __syncthreads();
    long long e0 = (long long)blockIdx.x * (TPB_P * EPT);
    long long EA = (long long)E_RB + E_BB;
    int bk[EPT], loc[EPT], pk[EPT];
    #pragma unroll
    for (int j = 0; j < EPT; ++j) {
        long long e = e0 + j * TPB_P + t;
        bk[j] = -1; loc[j] = 0; pk[j] = 0;
        if (e < EA) {
            int s, d;
            if (e < E_RB) { s = src_rb[e]; d = dst_rb[e]; }
            else          { long long e2 = e - E_RB; s = src_bb[e2]; d = NB + dst_bb[e2]; }
            bk[j] = d >> 7;
            pk[j] = (s << 7) | (d & 127);
            loc[j] = atomicAdd(&lcnt[bk[j]], 1);
        }
    }
    __syncthreads();
    for (int i = t; i < NBUCK; i += TPB_P) {
        int c = lcnt[i];
        wbase[i] = c ? atomicAdd(&gcurp[i * 16], c) : 0;
    }
    __syncthreads();
    #pragma unroll
    for (int j = 0; j < EPT; ++j) {
        if (bk[j] >= 0) {
            int gslot = wbase[bk[j]] + loc[j];
            if (gslot < (bk[j] + 1) * CAP)      // overflow guard (never fires)
                bins[gslot] = pk[j];
        }
    }
}

// ---------------- fused build+gather: bins read ONCE into LDS, sort, gather ----------
__global__ void __launch_bounds__(TPB2) buildgather_kernel(
        const __half* __restrict__ h_r16, const __half* __restrict__ h_b16,
        const int* __restrict__ bins, const int* __restrict__ gcurp,
        __half* __restrict__ mean16, int NB, int N2) {
    __shared__ int rawbuf[CAP];          // 8 KB  (bucket's packed edges)
    __shared__ int srcbuf[CAP];          // 8 KB  (slot-sorted srcs)
    __shared__ int lcnt[SLOTS];
    __shared__ int lbase[SLOTS];
    __shared__ int lcur[SLOTS];
    __shared__ int tmp[SLOTS];
    int t = threadIdx.x;
    int b = blockIdx.x;
    int start = b * CAP;
    int n = gcurp[b * 16] - start;       // final count for this bucket
    if (n > CAP) n = CAP;

    if (t < SLOTS) lcnt[t] = 0;
    __syncthreads();

    // phase A: coalesced single read of bins into LDS + per-slot histogram
    for (int i = t; i < n; i += TPB2) {
        int packed = bins[start + i];
        rawbuf[i] = packed;
        atomicAdd(&lcnt[packed & 127], 1);
    }
    __syncthreads();

    // phase B: exclusive scan of 128 slot counters
    if (t < SLOTS) tmp[t] = lcnt[t];
    __syncthreads();
    for (int off = 1; off < SLOTS; off <<= 1) {
        int x = (t >= off && t < SLOTS) ? tmp[t - off] : 0;
        __syncthreads();
        if (t < SLOTS) tmp[t] += x;
        __syncthreads();
    }
    if (t < SLOTS) { lbase[t] = tmp[t] - lcnt[t]; lcur[t] = tmp[t] - lcnt[t]; }
    __syncthreads();

    // phase C: LDS->LDS scatter, slot-sorted
    for (int i = t; i < n; i += TPB2) {
        int packed = rawbuf[i];
        int slot = atomicAdd(&lcur[packed & 127], 1);
        srcbuf[slot] = packed >> 7;
    }
    __syncthreads();

    // phase D: gather; 16 groups of 16 lanes; lane owns channels {2l,2l+1}
    int lane = t & 15, g = t >> 4;
    long long base_slot = (long long)b << 7;
    for (int sl = g; sl < SLOTS; sl += (TPB2 / 16)) {
        long long gd = base_slot + sl;
        if (gd >= N2) break;
        const __half* __restrict__ hs = (gd < NB) ? h_r16 : h_b16;
        int off = lbase[sl];
        int cnt = lcnt[sl];
        float ax = 0.0f, ay = 0.0f;
        int k = 0;
        for (; k + 4 <= cnt; k += 4) {
            int s0 = srcbuf[off + k];
            int s1 = srcbuf[off + k + 1];
            int s2 = srcbuf[off + k + 2];
            int s3 = srcbuf[off + k + 3];
            float2 f0 = __half22float2(*(const __half2*)(hs + (long long)s0 * H + 2 * lane));
            float2 f1 = __half22float2(*(const __half2*)(hs + (long long)s1 * H + 2 * lane));
            float2 f2 = __half22float2(*(const __half2*)(hs + (long long)s2 * H + 2 * lane));
            float2 f3 = __half22float2(*(const __half2*)(hs + (long long)s3 * H + 2 * lane));
            ax += (f0.x + f1.x) + (f2.x + f3.x);
            ay += (f0.y + f1.y) + (f2.y + f3.y);
        }
        for (; k < cnt; ++k) {
            int s = srcbuf[off + k];
            float2 f = __half22float2(*(const __half2*)(hs + (long long)s * H + 2 * lane));
            ax += f.x; ay += f.y;
        }
        float inv = 1.0f / fmaxf((float)cnt, 1.0f);
        *(__half2*)(mean16 + gd * H + 2 * lane) = __floats2half2_rn(ax * inv, ay * inv);
    }
}

// ---------------- fused head (thread = node, fp16 inputs, W broadcast from LDS) ----------
__global__ void __launch_bounds__(TPB) head_kernel(
        const __half* __restrict__ h_b16,
        const __half* __restrict__ mean16,   // [2NB, H]
        const float* __restrict__ Wl_rb,
        const float* __restrict__ bl_rb,
        const float* __restrict__ Wl_bb,
        const float* __restrict__ bl_bb,
        const float* __restrict__ Wr_rb,
        const float* __restrict__ Wr_bb,
        const float* __restrict__ Wo,
        const float* __restrict__ bo,
        float* __restrict__ y, int N) {
    __shared__ float sWl_rb[H][H];
    __shared__ float sWl_bb[H][H];
    __shared__ float sWr[H][H];
    __shared__ float sbl[H];
    __shared__ float sWo[H];
    __shared__ float sbo;

    int t = threadIdx.x;
    for (int i = t; i < H * H; i += blockDim.x) {
        ((float*)sWl_rb)[i] = Wl_rb[i];
        ((float*)sWl_bb)[i] = Wl_bb[i];
        ((float*)sWr)[i]    = Wr_rb[i] + Wr_bb[i];
    }
    if (t < H) {
        sbl[t] = bl_rb[t] + bl_bb[t];
        sWo[t] = Wo[t];
    }
    if (t == 0) sbo = bo[0];
    __syncthreads();

    int node = blockIdx.x * TPB + t;
    if (node >= N) return;

    const float4* pr = (const float4*)(mean16 + (long long)node * H);
    const float4* pb = (const float4*)(mean16 + ((long long)N + node) * H);
    const float4* ph = (const float4*)(h_b16 + (long long)node * H);

    float acc[H];
    #pragma unroll
    for (int j = 0; j < H; ++j) acc[j] = sbl[j];

    #pragma unroll
    for (int c = 0; c < 4; ++c) {            // 8 k-values per chunk
        float4 qr = pr[c];
        float4 qb = pb[c];
        float4 qh = ph[c];
        const __half2* hr = (const __half2*)&qr;
        const __half2* hb = (const __half2*)&qb;
        const __half2* hh = (const __half2*)&qh;
        #pragma unroll
        for (int u = 0; u < 4; ++u) {
            float2 fr = __half22float2(hr[u]);
            float2 fb = __half22float2(hb[u]);
            float2 fh = __half22float2(hh[u]);
            int k0 = c * 8 + u * 2;
            #pragma unroll
            for (int j = 0; j < H; ++j) {
                acc[j] = fmaf(fr.x, sWl_rb[k0][j], acc[j]);
                acc[j] = fmaf(fb.x, sWl_bb[k0][j], acc[j]);
                acc[j] = fmaf(fh.x, sWr[k0][j], acc[j]);
                acc[j] = fmaf(fr.y, sWl_rb[k0 + 1][j], acc[j]);
                acc[j] = fmaf(fb.y, sWl_bb[k0 + 1][j], acc[j]);
                acc[j] = fmaf(fh.y, sWr[k0 + 1][j], acc[j]);
            }
        }
    }

    float out = 0.0f;
    #pragma unroll
    for (int j = 0; j < H; ++j)
        out = fmaf(fmaxf(acc[j], 0.0f), sWo[j], out);
    y[node] = out + sbo;
}

extern "C" void kernel_launch(void* const* d_in, const int* in_sizes, int n_in,
                              void* d_out, int out_size, void* d_ws, size_t ws_size,
                              hipStream_t stream) {
    const float* x_bridge = (const float*)d_in[0];
    const float* x_road   = (const float*)d_in[1];
    const int* src_rb = (const int*)d_in[4];
    const int* dst_rb = (const int*)d_in[5];
    const int* src_bb = (const int*)d_in[6];
    const int* dst_bb = (const int*)d_in[7];
    const float* W_enc_b = (const float*)d_in[8];
    const float* b_enc_b = (const float*)d_in[9];
    const float* W_enc_r = (const float*)d_in[10];
    const float* b_enc_r = (const float*)d_in[11];
    const float* Wl_rb = (const float*)d_in[15];
    const float* bl_rb = (const float*)d_in[16];
    const float* Wr_rb = (const float*)d_in[17];
    const float* Wl_bb = (const float*)d_in[18];
    const float* bl_bb = (const float*)d_in[19];
    const float* Wr_bb = (const float*)d_in[20];
    const float* Wo = (const float*)d_in[21];
    const float* bo = (const float*)d_in[22];
    float* y = (float*)d_out;

    const int NB = in_sizes[0] / 16;
    const int NR = in_sizes[1] / 8;
    const int E_RB = in_sizes[4];
    const int E_BB = in_sizes[6];
    const int N2 = 2 * NB;
    const long long E_ALL = (long long)E_RB + E_BB;
    const int NBUCK = (N2 + SLOTS - 1) / SLOTS;     // 1563

    // Workspace layout (~45 MB)
    char* wp = (char*)d_ws;
    __half* h_r16  = (__half*)wp; wp += (size_t)NR * H * sizeof(__half);
    __half* h_b16  = (__half*)wp; wp += (size_t)NB * H * sizeof(__half);
    __half* mean16 = (__half*)wp; wp += (size_t)N2 * H * sizeof(__half);
    int* bins  = (int*)wp;       wp += (size_t)NBUCK * CAP * sizeof(int);
    int* gcurp = (int*)wp;       wp += (size_t)NBUCK * 16 * sizeof(int);

    // fused encoder (both node types) + gcurp cursor init
    {
        long long nodes = (long long)NB + NR;
        int blocks = (int)((nodes + (TPB / H) - 1) / (TPB / H));
        encoder_kernel<<<blocks, TPB, 0, stream>>>(x_bridge, x_road,
                                                   W_enc_b, b_enc_b, W_enc_r, b_enc_r,
                                                   h_b16, h_r16, NB, NR, gcurp, NBUCK);
    }

    // single edge pass: place into fixed-capacity bucket bins
    int nWGe = (int)((E_ALL + (TPB_P * EPT) - 1) / (TPB_P * EPT));   // 367
    place_kernel<<<nWGe, TPB_P, 0, stream>>>(src_rb, dst_rb, src_bb, dst_bb,
                                             gcurp, bins, E_RB, E_BB, NB, NBUCK);

    // fused per-bucket slot-sort (LDS) + gather -> mean16
    buildgather_kernel<<<NBUCK, TPB2, 0, stream>>>(h_r16, h_b16, bins, gcurp,
                                                   mean16, NB, N2);

    // fused head
    head_kernel<<<(NB + TPB - 1) / TPB, TPB, 0, stream>>>(h_b16, mean16,
                                                  Wl_rb, bl_rb, Wl_bb, bl_bb,
                                                  Wr_rb, Wr_bb, Wo, bo, y, NB);
}

// Round 13
// 104.657 us; speedup vs baseline: 1.1954x; 1.1954x over previous
//
#include <hip/hip_runtime.h>
#include <hip/hip_fp16.h>

#define H 32
#define TPB 256
#define TPB_P 256         // threads for place (367 WGs -> all CUs busy)
#define TPB2 256          // threads for fused build+gather
#define EPT 16            // edges per thread in place (4096 edges per WG)
#define SLOTS 128         // dst slots per bucket
#define CAP 2048          // fixed capacity per bucket (mean 1280, +21 sigma)
#define MAXBUCK 2048      // static LDS bound (actual NBUCK = 1563)

// ---------------- encoder: thread = node, vectorized loads, W broadcast from LDS ------
// nodes [0,NB) = bridge (FIN=16), [NB,NB+NR) = road (FIN=8). Also inits gcurp.
__global__ void __launch_bounds__(TPB) encoder_kernel(
        const float* __restrict__ x_b, const float* __restrict__ x_r,
        const float* __restrict__ W_b, const float* __restrict__ b_b,
        const float* __restrict__ W_r, const float* __restrict__ b_r,
        __half* __restrict__ h_b16, __half* __restrict__ h_r16,
        int NB, int NR,
        int* __restrict__ gcurp, int NBUCK) {
    int gid = blockIdx.x * TPB + threadIdx.x;
    if (gid < NBUCK) gcurp[gid * 16] = gid * CAP;

    __shared__ float sWb[16][H];
    __shared__ float sWr8[8][H];
    __shared__ float sbb[H];
    __shared__ float sbr[H];
    int t = threadIdx.x;
    for (int i = t; i < 16 * H; i += TPB) ((float*)sWb)[i] = W_b[i];
    for (int i = t; i < 8 * H; i += TPB) ((float*)sWr8)[i] = W_r[i];
    if (t < H) { sbb[t] = b_b[t]; sbr[t] = b_r[t]; }
    __syncthreads();

    long long node = gid;
    if (node < NB) {
        const float4* px = (const float4*)(x_b + node * 16);
        float acc[H];
        #pragma unroll
        for (int j = 0; j < H; ++j) acc[j] = sbb[j];
        #pragma unroll
        for (int c = 0; c < 4; ++c) {
            float4 q = px[c];
            float xs[4] = {q.x, q.y, q.z, q.w};
            #pragma unroll
            for (int u = 0; u < 4; ++u) {
                int k = c * 4 + u;
                #pragma unroll
                for (int j = 0; j < H; ++j)
                    acc[j] = fmaf(xs[u], sWb[k][j], acc[j]);
            }
        }
        __half2 o[H / 2];
        #pragma unroll
        for (int j2 = 0; j2 < H / 2; ++j2)
            o[j2] = __floats2half2_rn(fmaxf(acc[2 * j2], 0.0f), fmaxf(acc[2 * j2 + 1], 0.0f));
        float4* dst = (float4*)(h_b16 + node * H);
        const float4* src = (const float4*)o;
        dst[0] = src[0]; dst[1] = src[1]; dst[2] = src[2]; dst[3] = src[3];
    } else if (node < (long long)NB + NR) {
        long long m = node - NB;
        const float4* px = (const float4*)(x_r + m * 8);
        float acc[H];
        #pragma unroll
        for (int j = 0; j < H; ++j) acc[j] = sbr[j];
        #pragma unroll
        for (int c = 0; c < 2; ++c) {
            float4 q = px[c];
            float xs[4] = {q.x, q.y, q.z, q.w};
            #pragma unroll
            for (int u = 0; u < 4; ++u) {
                int k = c * 4 + u;
                #pragma unroll
                for (int j = 0; j < H; ++j)
                    acc[j] = fmaf(xs[u], sWr8[k][j], acc[j]);
            }
        }
        __half2 o[H / 2];
        #pragma unroll
        for (int j2 = 0; j2 < H / 2; ++j2)
            o[j2] = __floats2half2_rn(fmaxf(acc[2 * j2], 0.0f), fmaxf(acc[2 * j2 + 1], 0.0f));
        float4* dst = (float4*)(h_r16 + m * H);
        const float4* src = (const float4*)o;
        dst[0] = src[0]; dst[1] = src[1]; dst[2] = src[2]; dst[3] = src[3];
    }
}

// ---------------- place edges into fixed-capacity bucket bins ----------------
// concatenated dst space: rb -> d, bb -> NB + d.
// packed entry = (src << 7) | (slot & 127).
__global__ void __launch_bounds__(TPB_P) place_kernel(
        const int* __restrict__ src_rb, const int* __restrict__ dst_rb,
        const int* __restrict__ src_bb, const int* __restrict__ dst_bb,
        int* __restrict__ gcurp, int* __restrict__ bins,
        int E_RB, int E_BB, int NB, int NBUCK) {
    __shared__ int lcnt[MAXBUCK];
    __shared__ int wbase[MAXBUCK];
    int t = threadIdx.x;
    for (int i = t; i < MAXBUCK; i += TPB_P) lcnt[i] = 0;
    __syncthreads();
    long long e0 = (long long)blockIdx.x * (TPB_P * EPT);
    long long EA = (long long)E_RB + E_BB;
    int bk[EPT], loc[EPT], pk[EPT];
    #pragma unroll
    for (int j = 0; j < EPT; ++j) {
        long long e = e0 + j * TPB_P + t;
        bk[j] = -1; loc[j] = 0; pk[j] = 0;
        if (e < EA) {
            int s, d;
            if (e < E_RB) { s = src_rb[e]; d = dst_rb[e]; }
            else          { long long e2 = e - E_RB; s = src_bb[e2]; d = NB + dst_bb[e2]; }
            bk[j] = d >> 7;
            pk[j] = (s << 7) | (d & 127);
            loc[j] = atomicAdd(&lcnt[bk[j]], 1);
        }
    }
    __syncthreads();
    for (int i = t; i < NBUCK; i += TPB_P) {
        int c = lcnt[i];
        wbase[i] = c ? atomicAdd(&gcurp[i * 16], c) : 0;
    }
    __syncthreads();
    #pragma unroll
    for (int j = 0; j < EPT; ++j) {
        if (bk[j] >= 0) {
            int gslot = wbase[bk[j]] + loc[j];
            if (gslot < (bk[j] + 1) * CAP)      // overflow guard (never fires)
                bins[gslot] = pk[j];
        }
    }
}

// ---------------- fused build+gather: bins read ONCE into LDS, sort, gather ----------
__global__ void __launch_bounds__(TPB2) buildgather_kernel(
        const __half* __restrict__ h_r16, const __half* __restrict__ h_b16,
        const int* __restrict__ bins, const int* __restrict__ gcurp,
        __half* __restrict__ mean16, int NB, int N2) {
    __shared__ int rawbuf[CAP];          // 8 KB  (bucket's packed edges)
    __shared__ int srcbuf[CAP];          // 8 KB  (slot-sorted srcs)
    __shared__ int lcnt[SLOTS];
    __shared__ int lbase[SLOTS];
    __shared__ int lcur[SLOTS];
    __shared__ int tmp[SLOTS];
    int t = threadIdx.x;
    int b = blockIdx.x;
    int start = b * CAP;
    int n = gcurp[b * 16] - start;       // final count for this bucket
    if (n > CAP) n = CAP;

    if (t < SLOTS) lcnt[t] = 0;
    __syncthreads();

    // phase A: coalesced single read of bins into LDS + per-slot histogram
    for (int i = t; i < n; i += TPB2) {
        int packed = bins[start + i];
        rawbuf[i] = packed;
        atomicAdd(&lcnt[packed & 127], 1);
    }
    __syncthreads();

    // phase B: exclusive scan of 128 slot counters
    if (t < SLOTS) tmp[t] = lcnt[t];
    __syncthreads();
    for (int off = 1; off < SLOTS; off <<= 1) {
        int x = (t >= off && t < SLOTS) ? tmp[t - off] : 0;
        __syncthreads();
        if (t < SLOTS) tmp[t] += x;
        __syncthreads();
    }
    if (t < SLOTS) { lbase[t] = tmp[t] - lcnt[t]; lcur[t] = tmp[t] - lcnt[t]; }
    __syncthreads();

    // phase C: LDS->LDS scatter, slot-sorted
    for (int i = t; i < n; i += TPB2) {
        int packed = rawbuf[i];
        int slot = atomicAdd(&lcur[packed & 127], 1);
        srcbuf[slot] = packed >> 7;
    }
    __syncthreads();

    // phase D: gather; 16 groups of 16 lanes; lane owns channels {2l,2l+1}
    int lane = t & 15, g = t >> 4;
    long long base_slot = (long long)b << 7;
    for (int sl = g; sl < SLOTS; sl += (TPB2 / 16)) {
        long long gd = base_slot + sl;
        if (gd >= N2) break;
        const __half* __restrict__ hs = (gd < NB) ? h_r16 : h_b16;
        int off = lbase[sl];
        int cnt = lcnt[sl];
        float ax = 0.0f, ay = 0.0f;
        int k = 0;
        for (; k + 4 <= cnt; k += 4) {
            int s0 = srcbuf[off + k];
            int s1 = srcbuf[off + k + 1];
            int s2 = srcbuf[off + k + 2];
            int s3 = srcbuf[off + k + 3];
            float2 f0 = __half22float2(*(const __half2*)(hs + (long long)s0 * H + 2 * lane));
            float2 f1 = __half22float2(*(const __half2*)(hs + (long long)s1 * H + 2 * lane));
            float2 f2 = __half22float2(*(const __half2*)(hs + (long long)s2 * H + 2 * lane));
            float2 f3 = __half22float2(*(const __half2*)(hs + (long long)s3 * H + 2 * lane));
            ax += (f0.x + f1.x) + (f2.x + f3.x);
            ay += (f0.y + f1.y) + (f2.y + f3.y);
        }
        for (; k < cnt; ++k) {
            int s = srcbuf[off + k];
            float2 f = __half22float2(*(const __half2*)(hs + (long long)s * H + 2 * lane));
            ax += f.x; ay += f.y;
        }
        float inv = 1.0f / fmaxf((float)cnt, 1.0f);
        *(__half2*)(mean16 + gd * H + 2 * lane) = __floats2half2_rn(ax * inv, ay * inv);
    }
}

// ---------------- fused head (thread = node, fp16 inputs, W broadcast from LDS) ----------
__global__ void __launch_bounds__(TPB) head_kernel(
        const __half* __restrict__ h_b16,
        const __half* __restrict__ mean16,   // [2NB, H]
        const float* __restrict__ Wl_rb,
        const float* __restrict__ bl_rb,
        const float* __restrict__ Wl_bb,
        const float* __restrict__ bl_bb,
        const float* __restrict__ Wr_rb,
        const float* __restrict__ Wr_bb,
        const float* __restrict__ Wo,
        const float* __restrict__ bo,
        float* __restrict__ y, int N) {
    __shared__ float sWl_rb[H][H];
    __shared__ float sWl_bb[H][H];
    __shared__ float sWr[H][H];
    __shared__ float sbl[H];
    __shared__ float sWo[H];
    __shared__ float sbo;

    int t = threadIdx.x;
    for (int i = t; i < H * H; i += blockDim.x) {
        ((float*)sWl_rb)[i] = Wl_rb[i];
        ((float*)sWl_bb)[i] = Wl_bb[i];
        ((float*)sWr)[i]    = Wr_rb[i] + Wr_bb[i];
    }
    if (t < H) {
        sbl[t] = bl_rb[t] + bl_bb[t];
        sWo[t] = Wo[t];
    }
    if (t == 0) sbo = bo[0];
    __syncthreads();

    int node = blockIdx.x * TPB + t;
    if (node >= N) return;

    const float4* pr = (const float4*)(mean16 + (long long)node * H);
    const float4* pb = (const float4*)(mean16 + ((long long)N + node) * H);
    const float4* ph = (const float4*)(h_b16 + (long long)node * H);

    float acc[H];
    #pragma unroll
    for (int j = 0; j < H; ++j) acc[j] = sbl[j];

    #pragma unroll
    for (int c = 0; c < 4; ++c) {            // 8 k-values per chunk
        float4 qr = pr[c];
        float4 qb = pb[c];
        float4 qh = ph[c];
        const __half2* hr = (const __half2*)&qr;
        const __half2* hb = (const __half2*)&qb;
        const __half2* hh = (const __half2*)&qh;
        #pragma unroll
        for (int u = 0; u < 4; ++u) {
            float2 fr = __half22float2(hr[u]);
            float2 fb = __half22float2(hb[u]);
            float2 fh = __half22float2(hh[u]);
            int k0 = c * 8 + u * 2;
            #pragma unroll
            for (int j = 0; j < H; ++j) {
                acc[j] = fmaf(fr.x, sWl_rb[k0][j], acc[j]);
                acc[j] = fmaf(fb.x, sWl_bb[k0][j], acc[j]);
                acc[j] = fmaf(fh.x, sWr[k0][j], acc[j]);
                acc[j] = fmaf(fr.y, sWl_rb[k0 + 1][j], acc[j]);
                acc[j] = fmaf(fb.y, sWl_bb[k0 + 1][j], acc[j]);
                acc[j] = fmaf(fh.y, sWr[k0 + 1][j], acc[j]);
            }
        }
    }

    float out = 0.0f;
    #pragma unroll
    for (int j = 0; j < H; ++j)
        out = fmaf(fmaxf(acc[j], 0.0f), sWo[j], out);
    y[node] = out + sbo;
}

extern "C" void kernel_launch(void* const* d_in, const int* in_sizes, int n_in,
                              void* d_out, int out_size, void* d_ws, size_t ws_size,
                              hipStream_t stream) {
    const float* x_bridge = (const float*)d_in[0];
    const float* x_road   = (const float*)d_in[1];
    const int* src_rb = (const int*)d_in[4];
    const int* dst_rb = (const int*)d_in[5];
    const int* src_bb = (const int*)d_in[6];
    const int* dst_bb = (const int*)d_in[7];
    const float* W_enc_b = (const float*)d_in[8];
    const float* b_enc_b = (const float*)d_in[9];
    const float* W_enc_r = (const float*)d_in[10];
    const float* b_enc_r = (const float*)d_in[11];
    const float* Wl_rb = (const float*)d_in[15];
    const float* bl_rb = (const float*)d_in[16];
    const float* Wr_rb = (const float*)d_in[17];
    const float* Wl_bb = (const float*)d_in[18];
    const float* bl_bb = (const float*)d_in[19];
    const float* Wr_bb = (const float*)d_in[20];
    const float* Wo = (const float*)d_in[21];
    const float* bo = (const float*)d_in[22];
    float* y = (float*)d_out;

    const int NB = in_sizes[0] / 16;
    const int NR = in_sizes[1] / 8;
    const int E_RB = in_sizes[4];
    const int E_BB = in_sizes[6];
    const int N2 = 2 * NB;
    const long long E_ALL = (long long)E_RB + E_BB;
    const int NBUCK = (N2 + SLOTS - 1) / SLOTS;     // 1563

    // Workspace layout (~45 MB)
    char* wp = (char*)d_ws;
    __half* h_r16  = (__half*)wp; wp += (size_t)NR * H * sizeof(__half);
    __half* h_b16  = (__half*)wp; wp += (size_t)NB * H * sizeof(__half);
    __half* mean16 = (__half*)wp; wp += (size_t)N2 * H * sizeof(__half);
    int* bins  = (int*)wp;       wp += (size_t)NBUCK * CAP * sizeof(int);
    int* gcurp = (int*)wp;       wp += (size_t)NBUCK * 16 * sizeof(int);

    // thread-per-node encoder (both node types) + gcurp cursor init
    {
        long long nodes = (long long)NB + NR;
        int blocks = (int)((nodes + TPB - 1) / TPB);
        encoder_kernel<<<blocks, TPB, 0, stream>>>(x_bridge, x_road,
                                                   W_enc_b, b_enc_b, W_enc_r, b_enc_r,
                                                   h_b16, h_r16, NB, NR, gcurp, NBUCK);
    }

    // single edge pass: place into fixed-capacity bucket bins
    int nWGe = (int)((E_ALL + (TPB_P * EPT) - 1) / (TPB_P * EPT));   // 367
    place_kernel<<<nWGe, TPB_P, 0, stream>>>(src_rb, dst_rb, src_bb, dst_bb,
                                             gcurp, bins, E_RB, E_BB, NB, NBUCK);

    // fused per-bucket slot-sort (LDS) + gather -> mean16
    buildgather_kernel<<<NBUCK, TPB2, 0, stream>>>(h_r16, h_b16, bins, gcurp,
                                                   mean16, NB, N2);

    // fused head
    head_kernel<<<(NB + TPB - 1) / TPB, TPB, 0, stream>>>(h_b16, mean16,
                                                  Wl_rb, bl_rb, Wl_bb, bl_bb,
                                                  Wr_rb, Wr_bb, Wo, bo, y, NB);
}

// Round 14
// 103.505 us; speedup vs baseline: 1.2087x; 1.0111x over previous
//
#include <hip/hip_runtime.h>
#include <hip/hip_fp16.h>

#define H 32
#define TPB 256
#define TPB_P 256         // threads for place
#define TPB2 256          // threads for fused build+gather
#define EPT 16            // edges per thread in place (4096 edges per WG)
#define SLOTS 128         // dst slots per bucket
#define CAP 2048          // fixed capacity per bucket (mean 1280, +21 sigma)
#define MAXBUCK 2048      // static LDS bound (actual NBUCK = 1563)

// ---------------- encoder: thread = node, vectorized loads, W broadcast from LDS ------
// nodes [0,NB) = bridge (FIN=16), [NB,NB+NR) = road (FIN=8). Also inits gcurp.
__global__ void __launch_bounds__(TPB) encoder_kernel(
        const float* __restrict__ x_b, const float* __restrict__ x_r,
        const float* __restrict__ W_b, const float* __restrict__ b_b,
        const float* __restrict__ W_r, const float* __restrict__ b_r,
        __half* __restrict__ h_b16, __half* __restrict__ h_r16,
        int NB, int NR,
        int* __restrict__ gcurp, int NBUCK) {
    int gid = blockIdx.x * TPB + threadIdx.x;
    if (gid < NBUCK) gcurp[gid * 16] = gid * CAP;

    __shared__ float sWb[16][H];
    __shared__ float sWr8[8][H];
    __shared__ float sbb[H];
    __shared__ float sbr[H];
    int t = threadIdx.x;
    for (int i = t; i < 16 * H; i += TPB) ((float*)sWb)[i] = W_b[i];
    for (int i = t; i < 8 * H; i += TPB) ((float*)sWr8)[i] = W_r[i];
    if (t < H) { sbb[t] = b_b[t]; sbr[t] = b_r[t]; }
    __syncthreads();

    long long node = gid;
    if (node < NB) {
        const float4* px = (const float4*)(x_b + node * 16);
        float acc[H];
        #pragma unroll
        for (int j = 0; j < H; ++j) acc[j] = sbb[j];
        #pragma unroll
        for (int c = 0; c < 4; ++c) {
            float4 q = px[c];
            float xs[4] = {q.x, q.y, q.z, q.w};
            #pragma unroll
            for (int u = 0; u < 4; ++u) {
                int k = c * 4 + u;
                #pragma unroll
                for (int j = 0; j < H; ++j)
                    acc[j] = fmaf(xs[u], sWb[k][j], acc[j]);
            }
        }
        __half2 o[H / 2];
        #pragma unroll
        for (int j2 = 0; j2 < H / 2; ++j2)
            o[j2] = __floats2half2_rn(fmaxf(acc[2 * j2], 0.0f), fmaxf(acc[2 * j2 + 1], 0.0f));
        float4* dst = (float4*)(h_b16 + node * H);
        const float4* src = (const float4*)o;
        dst[0] = src[0]; dst[1] = src[1]; dst[2] = src[2]; dst[3] = src[3];
    } else if (node < (long long)NB + NR) {
        long long m = node - NB;
        const float4* px = (const float4*)(x_r + m * 8);
        float acc[H];
        #pragma unroll
        for (int j = 0; j < H; ++j) acc[j] = sbr[j];
        #pragma unroll
        for (int c = 0; c < 2; ++c) {
            float4 q = px[c];
            float xs[4] = {q.x, q.y, q.z, q.w};
            #pragma unroll
            for (int u = 0; u < 4; ++u) {
                int k = c * 4 + u;
                #pragma unroll
                for (int j = 0; j < H; ++j)
                    acc[j] = fmaf(xs[u], sWr8[k][j], acc[j]);
            }
        }
        __half2 o[H / 2];
        #pragma unroll
        for (int j2 = 0; j2 < H / 2; ++j2)
            o[j2] = __floats2half2_rn(fmaxf(acc[2 * j2], 0.0f), fmaxf(acc[2 * j2 + 1], 0.0f));
        float4* dst = (float4*)(h_r16 + m * H);
        const float4* src = (const float4*)o;
        dst[0] = src[0]; dst[1] = src[1]; dst[2] = src[2]; dst[3] = src[3];
    }
}

// ---------------- place edges into fixed-capacity bucket bins ----------------
__global__ void __launch_bounds__(TPB_P) place_kernel(
        const int* __restrict__ src_rb, const int* __restrict__ dst_rb,
        const int* __restrict__ src_bb, const int* __restrict__ dst_bb,
        int* __restrict__ gcurp, int* __restrict__ bins,
        int E_RB, int E_BB, int NB, int NBUCK) {
    __shared__ int lcnt[MAXBUCK];
    __shared__ int wbase[MAXBUCK];
    int t = threadIdx.x;
    for (int i = t; i < MAXBUCK; i += TPB_P) lcnt[i] = 0;
    __syncthreads();
    long long e0 = (long long)blockIdx.x * (TPB_P * EPT);
    long long EA = (long long)E_RB + E_BB;
    int bk[EPT], loc[EPT], pk[EPT];
    #pragma unroll
    for (int j = 0; j < EPT; ++j) {
        long long e = e0 + j * TPB_P + t;
        bk[j] = -1; loc[j] = 0; pk[j] = 0;
        if (e < EA) {
            int s, d;
            if (e < E_RB) { s = src_rb[e]; d = dst_rb[e]; }
            else          { long long e2 = e - E_RB; s = src_bb[e2]; d = NB + dst_bb[e2]; }
            bk[j] = d >> 7;
            pk[j] = (s << 7) | (d & 127);
            loc[j] = atomicAdd(&lcnt[bk[j]], 1);
        }
    }
    __syncthreads();
    for (int i = t; i < NBUCK; i += TPB_P) {
        int c = lcnt[i];
        wbase[i] = c ? atomicAdd(&gcurp[i * 16], c) : 0;
    }
    __syncthreads();
    #pragma unroll
    for (int j = 0; j < EPT; ++j) {
        if (bk[j] >= 0) {
            int gslot = wbase[bk[j]] + loc[j];
            if (gslot < (bk[j] + 1) * CAP)      // overflow guard (never fires)
                bins[gslot] = pk[j];
        }
    }
}

// ---------------- fused build+gather: int4 bins read, sort, unroll-8 gather ----------
__global__ void __launch_bounds__(TPB2) buildgather_kernel(
        const __half* __restrict__ h_r16, const __half* __restrict__ h_b16,
        const int* __restrict__ bins, const int* __restrict__ gcurp,
        __half* __restrict__ mean16, int NB, int N2) {
    __shared__ int rawbuf[CAP];          // 8 KB  (bucket's packed edges)
    __shared__ int srcbuf[CAP];          // 8 KB  (slot-sorted srcs)
    __shared__ int lcnt[SLOTS];
    __shared__ int lbase[SLOTS];
    __shared__ int lcur[SLOTS];
    __shared__ int tmp[SLOTS];
    int t = threadIdx.x;
    int b = blockIdx.x;
    int start = b * CAP;                 // CAP multiple of 4 -> int4-aligned
    int n = gcurp[b * 16] - start;       // final count for this bucket
    if (n > CAP) n = CAP;

    if (t < SLOTS) lcnt[t] = 0;
    __syncthreads();

    // phase A: int4 read of bins into LDS + per-slot histogram (4 edges/thread/iter)
    {
        int n4 = n >> 2;
        const int4* bins4 = (const int4*)(bins + start);
        for (int i = t; i < n4; i += TPB2) {
            int4 p = bins4[i];
            ((int4*)rawbuf)[i] = p;
            atomicAdd(&lcnt[p.x & 127], 1);
            atomicAdd(&lcnt[p.y & 127], 1);
            atomicAdd(&lcnt[p.z & 127], 1);
            atomicAdd(&lcnt[p.w & 127], 1);
        }
        // tail
        for (int i = (n4 << 2) + t; i < n; i += TPB2) {
            int packed = bins[start + i];
            rawbuf[i] = packed;
            atomicAdd(&lcnt[packed & 127], 1);
        }
    }
    __syncthreads();

    // phase B: exclusive scan of 128 slot counters
    if (t < SLOTS) tmp[t] = lcnt[t];
    __syncthreads();
    for (int off = 1; off < SLOTS; off <<= 1) {
        int x = (t >= off && t < SLOTS) ? tmp[t - off] : 0;
        __syncthreads();
        if (t < SLOTS) tmp[t] += x;
        __syncthreads();
    }
    if (t < SLOTS) { lbase[t] = tmp[t] - lcnt[t]; lcur[t] = tmp[t] - lcnt[t]; }
    __syncthreads();

    // phase C: LDS->LDS scatter, slot-sorted
    for (int i = t; i < n; i += TPB2) {
        int packed = rawbuf[i];
        int slot = atomicAdd(&lcur[packed & 127], 1);
        srcbuf[slot] = packed >> 7;
    }
    __syncthreads();

    // phase D: gather; 16 groups of 16 lanes; lane owns channels {2l,2l+1}; 8/4/1 ILP
    int lane = t & 15, g = t >> 4;
    long long base_slot = (long long)b << 7;
    for (int sl = g; sl < SLOTS; sl += (TPB2 / 16)) {
        long long gd = base_slot + sl;
        if (gd >= N2) break;
        const __half* __restrict__ hs = (gd < NB) ? h_r16 : h_b16;
        int off = lbase[sl];
        int cnt = lcnt[sl];
        float ax = 0.0f, ay = 0.0f;
        int k = 0;
        for (; k + 8 <= cnt; k += 8) {
            int s[8];
            #pragma unroll
            for (int j = 0; j < 8; ++j) s[j] = srcbuf[off + k + j];
            float2 f[8];
            #pragma unroll
            for (int j = 0; j < 8; ++j)
                f[j] = __half22float2(*(const __half2*)(hs + (long long)s[j] * H + 2 * lane));
            #pragma unroll
            for (int j = 0; j < 8; ++j) { ax += f[j].x; ay += f[j].y; }
        }
        if (k + 4 <= cnt) {
            int s[4];
            #pragma unroll
            for (int j = 0; j < 4; ++j) s[j] = srcbuf[off + k + j];
            float2 f[4];
            #pragma unroll
            for (int j = 0; j < 4; ++j)
                f[j] = __half22float2(*(const __half2*)(hs + (long long)s[j] * H + 2 * lane));
            #pragma unroll
            for (int j = 0; j < 4; ++j) { ax += f[j].x; ay += f[j].y; }
            k += 4;
        }
        for (; k < cnt; ++k) {
            int s = srcbuf[off + k];
            float2 f = __half22float2(*(const __half2*)(hs + (long long)s * H + 2 * lane));
            ax += f.x; ay += f.y;
        }
        float inv = 1.0f / fmaxf((float)cnt, 1.0f);
        *(__half2*)(mean16 + gd * H + 2 * lane) = __floats2half2_rn(ax * inv, ay * inv);
    }
}

// ---------------- fused head (thread = node, fp16 inputs, W broadcast from LDS) ----------
__global__ void __launch_bounds__(TPB) head_kernel(
        const __half* __restrict__ h_b16,
        const __half* __restrict__ mean16,   // [2NB, H]
        const float* __restrict__ Wl_rb,
        const float* __restrict__ bl_rb,
        const float* __restrict__ Wl_bb,
        const float* __restrict__ bl_bb,
        const float* __restrict__ Wr_rb,
        const float* __restrict__ Wr_bb,
        const float* __restrict__ Wo,
        const float* __restrict__ bo,
        float* __restrict__ y, int N) {
    __shared__ float sWl_rb[H][H];
    __shared__ float sWl_bb[H][H];
    __shared__ float sWr[H][H];
    __shared__ float sbl[H];
    __shared__ float sWo[H];
    __shared__ float sbo;

    int t = threadIdx.x;
    for (int i = t; i < H * H; i += blockDim.x) {
        ((float*)sWl_rb)[i] = Wl_rb[i];
        ((float*)sWl_bb)[i] = Wl_bb[i];
        ((float*)sWr)[i]    = Wr_rb[i] + Wr_bb[i];
    }
    if (t < H) {
        sbl[t] = bl_rb[t] + bl_bb[t];
        sWo[t] = Wo[t];
    }
    if (t == 0) sbo = bo[0];
    __syncthreads();

    int node = blockIdx.x * TPB + t;
    if (node >= N) return;

    const float4* pr = (const float4*)(mean16 + (long long)node * H);
    const float4* pb = (const float4*)(mean16 + ((long long)N + node) * H);
    const float4* ph = (const float4*)(h_b16 + (long long)node * H);

    float acc[H];
    #pragma unroll
    for (int j = 0; j < H; ++j) acc[j] = sbl[j];

    #pragma unroll
    for (int c = 0; c < 4; ++c) {            // 8 k-values per chunk
        float4 qr = pr[c];
        float4 qb = pb[c];
        float4 qh = ph[c];
        const __half2* hr = (const __half2*)&qr;
        const __half2* hb = (const __half2*)&qb;
        const __half2* hh = (const __half2*)&qh;
        #pragma unroll
        for (int u = 0; u < 4; ++u) {
            float2 fr = __half22float2(hr[u]);
            float2 fb = __half22float2(hb[u]);
            float2 fh = __half22float2(hh[u]);
            int k0 = c * 8 + u * 2;
            #pragma unroll
            for (int j = 0; j < H; ++j) {
                acc[j] = fmaf(fr.x, sWl_rb[k0][j], acc[j]);
                acc[j] = fmaf(fb.x, sWl_bb[k0][j], acc[j]);
                acc[j] = fmaf(fh.x, sWr[k0][j], acc[j]);
                acc[j] = fmaf(fr.y, sWl_rb[k0 + 1][j], acc[j]);
                acc[j] = fmaf(fb.y, sWl_bb[k0 + 1][j], acc[j]);
                acc[j] = fmaf(fh.y, sWr[k0 + 1][j], acc[j]);
            }
        }
    }

    float out = 0.0f;
    #pragma unroll
    for (int j = 0; j < H; ++j)
        out = fmaf(fmaxf(acc[j], 0.0f), sWo[j], out);
    y[node] = out + sbo;
}

extern "C" void kernel_launch(void* const* d_in, const int* in_sizes, int n_in,
                              void* d_out, int out_size, void* d_ws, size_t ws_size,
                              hipStream_t stream) {
    const float* x_bridge = (const float*)d_in[0];
    const float* x_road   = (const float*)d_in[1];
    const int* src_rb = (const int*)d_in[4];
    const int* dst_rb = (const int*)d_in[5];
    const int* src_bb = (const int*)d_in[6];
    const int* dst_bb = (const int*)d_in[7];
    const float* W_enc_b = (const float*)d_in[8];
    const float* b_enc_b = (const float*)d_in[9];
    const float* W_enc_r = (const float*)d_in[10];
    const float* b_enc_r = (const float*)d_in[11];
    const float* Wl_rb = (const float*)d_in[15];
    const float* bl_rb = (const float*)d_in[16];
    const float* Wr_rb = (const float*)d_in[17];
    const float* Wl_bb = (const float*)d_in[18];
    const float* bl_bb = (const float*)d_in[19];
    const float* Wr_bb = (const float*)d_in[20];
    const float* Wo = (const float*)d_in[21];
    const float* bo = (const float*)d_in[22];
    float* y = (float*)d_out;

    const int NB = in_sizes[0] / 16;
    const int NR = in_sizes[1] / 8;
    const int E_RB = in_sizes[4];
    const int E_BB = in_sizes[6];
    const int N2 = 2 * NB;
    const long long E_ALL = (long long)E_RB + E_BB;
    const int NBUCK = (N2 + SLOTS - 1) / SLOTS;     // 1563

    // Workspace layout (~45 MB)
    char* wp = (char*)d_ws;
    __half* h_r16  = (__half*)wp; wp += (size_t)NR * H * sizeof(__half);
    __half* h_b16  = (__half*)wp; wp += (size_t)NB * H * sizeof(__half);
    __half* mean16 = (__half*)wp; wp += (size_t)N2 * H * sizeof(__half);
    int* bins  = (int*)wp;       wp += (size_t)NBUCK * CAP * sizeof(int);
    int* gcurp = (int*)wp;       wp += (size_t)NBUCK * 16 * sizeof(int);

    // thread-per-node encoder (both node types) + gcurp cursor init
    {
        long long nodes = (long long)NB + NR;
        int blocks = (int)((nodes + TPB - 1) / TPB);
        encoder_kernel<<<blocks, TPB, 0, stream>>>(x_bridge, x_road,
                                                   W_enc_b, b_enc_b, W_enc_r, b_enc_r,
                                                   h_b16, h_r16, NB, NR, gcurp, NBUCK);
    }

    // single edge pass: place into fixed-capacity bucket bins
    int nWGe = (int)((E_ALL + (TPB_P * EPT) - 1) / (TPB_P * EPT));   // 367
    place_kernel<<<nWGe, TPB_P, 0, stream>>>(src_rb, dst_rb, src_bb, dst_bb,
                                             gcurp, bins, E_RB, E_BB, NB, NBUCK);

    // fused per-bucket slot-sort (LDS) + gather -> mean16
    buildgather_kernel<<<NBUCK, TPB2, 0, stream>>>(h_r16, h_b16, bins, gcurp,
                                                   mean16, NB, N2);

    // fused head
    head_kernel<<<(NB + TPB - 1) / TPB, TPB, 0, stream>>>(h_b16, mean16,
                                                  Wl_rb, bl_rb, Wl_bb, bl_bb,
                                                  Wr_rb, Wr_bb, Wo, bo, y, NB);
}